// Round 7
// baseline (464.169 us; speedup 1.0000x reference)
//
#include <hip/hip_runtime.h>
#include <math.h>

// Focal_loss2 — single fused dispatch, one-quad-per-thread max-TLP version.
//   neg: w = sigmoid(x)^2 * (gt==-1) * (x is 3x3x3 local max); loss += softplus(x)*w
//        local-max test in logit space (monotone sigmoid; validated R3-R5, absmax 0.0)
//   pos: 64 coords/batch/level gather; w1=(1-sigmoid)^2; per-(b,tag) min of w1
// ws (floats): [4]=losspos_a [5]=cntpos_a [6]=losspos_b [7]=cntpos_b [8]=block counter
//              [16+2s],[17+2s] s<64: level-a loss/w slots; [144+2s],[145+2s]: level-b
// out: [0]=cls_loss_pos [1]=cls_loss_neg [2]=count_pos [3]=count_neg
//      [4]=wsum_pos [5]=wsum_neg [6..37]=pred_prob_min[2][B=2][T=8]

#define NBLK_A 8192   // 4 vol x 128 z x 16 y-octets -> 256 thr = 8 y x 32 xq
#define NBLK_B 1024   // 4 vol x  64 z x  4 y-16s    -> 256 thr = 16 y x 16 xq
#define NBLK_TOTAL (NBLK_A + NBLK_B + 1)

__device__ __forceinline__ float fmax3(float a, float b, float c) {
    return fmaxf(a, fmaxf(b, c));
}

__device__ __forceinline__ float4 fmax3v(float4 a, float4 b, float4 c) {
    return make_float4(fmax3(a.x, b.x, c.x), fmax3(a.y, b.y, c.y),
                       fmax3(a.z, b.z, c.z), fmax3(a.w, b.w, c.w));
}

// One thread = one output quad. 9 stencil row-quads + 1 gt quad issued as a
// single load burst; sched_barrier(0) forbids the scheduler from sinking the
// folds into the burst (R2/R5 post-mortem: compiler serialized loads 3-deep).
// x-halo via wave shuffle (xq contiguous; group edges use the clamp override),
// y/z boundary via index clamping (duplicates an in-window value, max unchanged).
template <int D, int LOG2D, int XQ>
__device__ __forceinline__ void neg_quad(
    const float* __restrict__ logits, const float* __restrict__ gt,
    int vol, int z, int y, int xq, float& loss, float& wsum)
{
    const int x0 = xq << 2;
    const int zm = z > 0 ? z - 1 : 0, zp = z < D - 1 ? z + 1 : z;
    const int ym = y > 0 ? y - 1 : 0, yp = y < D - 1 ? y + 1 : y;
    const float* vb = logits + (vol << (3 * LOG2D));
    const int zz[3] = {zm, z, zp};
    const int yy[3] = {ym, y, yp};

    float4 r[9];
#pragma unroll
    for (int i = 0; i < 3; ++i)
#pragma unroll
        for (int j = 0; j < 3; ++j)
            r[i * 3 + j] = *(const float4*)(vb + (zz[i] << (2 * LOG2D)) +
                                            (yy[j] << LOG2D) + x0);
    float4 gq = *(const float4*)(gt + (vol << (3 * LOG2D)) +
                                 (z << (2 * LOG2D)) + (y << LOG2D) + x0);
    __builtin_amdgcn_sched_barrier(0);  // keep the 10-load burst intact

    // fold all 9 rows (z- and y-window combined) -> per-column max
    float4 cz = fmax3v(fmax3v(r[0], r[1], r[2]),
                       fmax3v(r[3], r[4], r[5]),
                       fmax3v(r[6], r[7], r[8]));
    float4 c = r[4];  // center row (z, y)

    float lco = __shfl_up(cz.w, 1);   if (xq == 0)      lco = cz.x;
    float rco = __shfl_down(cz.x, 1); if (xq == XQ - 1) rco = cz.w;
    float m0 = fmax3(lco, cz.x, cz.y);
    float m1 = fmax3(cz.x, cz.y, cz.z);
    float m2 = fmax3(cz.y, cz.z, cz.w);
    float m3 = fmax3(cz.z, cz.w, rco);

    float ms[4] = {m0, m1, m2, m3};
    float cs[4] = {c.x, c.y, c.z, c.w};
    float gs[4] = {gq.x, gq.y, gq.z, gq.w};
#pragma unroll
    for (int k = 0; k < 4; ++k) {
        if (gs[k] == -1.0f && ms[k] == cs[k]) {
            float e = __expf(cs[k]);                  // e^x
            float u = __builtin_amdgcn_rcpf(1.0f + e);
            float sc = e * u;                         // sigmoid(x)
            float wv = sc * sc;
            wsum += wv;
            loss += (-__logf(u)) * wv;                // softplus(x)
        }
    }
}

__global__ __launch_bounds__(256, 8) void fused_kernel(
    const float* __restrict__ la, const float* __restrict__ lb,
    const float* __restrict__ ga, const float* __restrict__ gb,
    const int* __restrict__ conn_a, const int* __restrict__ conn_b,
    const int* __restrict__ coord_a, const int* __restrict__ coord_b,
    float* __restrict__ ws, float* __restrict__ out)
{
    __shared__ float sred[8];
    __shared__ float w1s[128];
    __shared__ float tgf[128];
    __shared__ int lastFlag;
    const int bid = blockIdx.x;
    const int t = threadIdx.x;
    float loss = 0.0f, wsum = 0.0f;
    int slotBase = -1;

    if (bid < NBLK_A) {
        // level a: D=128. xq = t&31, yi = t>>5 (8 y per block)
        slotBase = 16;
        const int vol = bid >> 11;             // 2048 blocks per volume
        const int rem = bid & 2047;
        const int z = rem >> 4, yo = rem & 15; // 128 z x 16 y-octets
        neg_quad<128, 7, 32>(la, ga, vol, z, yo * 8 + (t >> 5), t & 31,
                             loss, wsum);
    } else if (bid < NBLK_A + NBLK_B) {
        // level b: D=64. xq = t&15, yi = t>>4 (16 y per block)
        slotBase = 144;
        const int b2 = bid - NBLK_A;
        const int vol = b2 >> 8;               // 256 blocks per volume
        const int rem = b2 & 255;
        const int z = rem >> 2, yo = rem & 3;  // 64 z x 4 y-16s
        neg_quad<64, 6, 16>(lb, gb, vol, z, yo * 16 + (t >> 4), t & 15,
                            loss, wsum);
    } else {
        // pos block: both levels, 128 active threads
        for (int level = 0; level < 2; ++level) {
            const float* logits = level ? lb : la;
            const int* conn = level ? conn_b : conn_a;
            const int* coord = level ? coord_b : coord_a;
            const int D = level ? 64 : 128;
            float li = 0.0f, ci = 0.0f;
            if (t < 128) {
                const int* c4 = coord + t * 4;
                int a = c4[0], zz = c4[1], yy = c4[2], xx = c4[3];
                bool valid = a > -1;
                int aa = valid ? a : 0, z2 = valid ? zz : 0,
                    y2 = valid ? yy : 0, x2 = valid ? xx : 0;
                int b = t >> 6;
                int off = (((b * 2 + aa) * D + z2) * D + y2) * D + x2;
                float lp = logits[off];
                int tag = conn[off];
                float s = 1.0f / (1.0f + expf(lp));   // 1 - sigmoid(lp)
                float w1 = s * s;
                float vf = valid ? 1.0f : 0.0f;
                float sp = fmaxf(-lp, 0.0f) + log1pf(expf(-fabsf(lp)));  // softplus(-lp)
                li = sp * w1 * vf;
                ci = w1 * vf;
                w1s[t] = w1;
                tgf[t] = (float)(valid ? tag : -1);
            }
            for (int o = 32; o; o >>= 1) {
                li += __shfl_down(li, o);
                ci += __shfl_down(ci, o);
            }
            if ((t & 63) == 0) { sred[t >> 6] = li; sred[4 + (t >> 6)] = ci; }
            __syncthreads();
            if (t == 0) {
                atomicAdd(ws + 4 + 2 * level, sred[0] + sred[1] + sred[2] + sred[3]);
                atomicAdd(ws + 5 + 2 * level, sred[4] + sred[5] + sred[6] + sred[7]);
            }
            if (t < 16) {
                int bb = t >> 3, tg = t & 7;
                float mn = INFINITY;
                for (int i = 0; i < 64; ++i) {
                    int j = bb * 64 + i;
                    if (tgf[j] == (float)tg) mn = fminf(mn, w1s[j]);
                }
                out[6 + level * 16 + bb * 8 + tg] = isinf(mn) ? -1.0f : mn;
            }
            __syncthreads();
        }
    }

    if (slotBase >= 0) {
        for (int o = 32; o; o >>= 1) {
            loss += __shfl_down(loss, o);
            wsum += __shfl_down(wsum, o);
        }
        if ((t & 63) == 0) { sred[t >> 6] = loss; sred[4 + (t >> 6)] = wsum; }
        __syncthreads();
        if (t == 0) {
            float L = sred[0] + sred[1] + sred[2] + sred[3];
            float W = sred[4] + sred[5] + sred[6] + sred[7];
            if (L != 0.0f || W != 0.0f) {
                const int s = slotBase + 2 * (bid & 63);
                atomicAdd(ws + s, L);
                atomicAdd(ws + s + 1, W);
            }
        }
    }

    // last-block finalize (cooperative)
    __syncthreads();
    if (t == 0) {
        __threadfence();
        unsigned int old = atomicAdd((unsigned int*)(ws + 8), 1u);
        lastFlag = (old == NBLK_TOTAL - 1) ? 1 : 0;
    }
    __syncthreads();
    if (lastFlag) {
        // threads 0..63 read level-a slots, 64..127 level-b (atomic reads bypass L1)
        float L = 0.0f, W = 0.0f;
        if (t < 128) {
            const int base = (t < 64) ? 16 : 144;
            const int i = t & 63;
            L = atomicAdd(ws + base + 2 * i, 0.0f);
            W = atomicAdd(ws + base + 2 * i + 1, 0.0f);
        }
        for (int o = 32; o; o >>= 1) {
            L += __shfl_down(L, o);
            W += __shfl_down(W, o);
        }
        if ((t & 63) == 0 && t < 128) { sred[t >> 6] = L; sred[4 + (t >> 6)] = W; }
        __syncthreads();
        if (t == 0) {
            float lA = sred[0], lB = sred[1];
            float wA = sred[4], wB = sred[5];
            float p4 = atomicAdd(ws + 4, 0.0f);
            float p5 = atomicAdd(ws + 5, 0.0f);
            float p6 = atomicAdd(ws + 6, 0.0f);
            float p7 = atomicAdd(ws + 7, 0.0f);
            out[0] = p4 * 2.0f + p6;   // cls_loss_pos (POS_FACTOR {2,1})
            out[1] = lA * 2.0f + lB;   // cls_loss_neg (NEG_FACTOR {2,1})
            out[2] = p5 + p7;          // count_pos
            out[3] = wA + wB;          // count_neg
            out[4] = p5 * 2.0f + p7;   // wsum_pos (anchor factor == 1)
            out[5] = wA * 2.0f + wB;   // wsum_neg
        }
    }
}

extern "C" void kernel_launch(void* const* d_in, const int* in_sizes, int n_in,
                              void* d_out, int out_size, void* d_ws, size_t ws_size,
                              hipStream_t stream) {
    const float* logits_a = (const float*)d_in[0];
    const float* logits_b = (const float*)d_in[1];
    const float* prob_a   = (const float*)d_in[2];
    const float* prob_b   = (const float*)d_in[3];
    const int*   conn_a   = (const int*)d_in[4];
    const int*   conn_b   = (const int*)d_in[5];
    const int*   coord_a  = (const int*)d_in[6];
    const int*   coord_b  = (const int*)d_in[7];
    float* out = (float*)d_out;
    float* ws  = (float*)d_ws;

    hipMemsetAsync(ws, 0, 272 * sizeof(float), stream);
    fused_kernel<<<NBLK_TOTAL, 256, 0, stream>>>(
        logits_a, logits_b, prob_a, prob_b,
        conn_a, conn_b, coord_a, coord_b, ws, out);
}

// Round 8
// 182.341 us; speedup vs baseline: 2.5456x; 2.5456x over previous
//
#include <hip/hip_runtime.h>
#include <math.h>

// Focal_loss2 — single fused dispatch, barrier-free rolling y-march stencil
// (R4 structure, 77 µs) + XCD-aware block swizzle (R7).
//   neg: w = sigmoid(x)^2 * (gt==-1) * (x is 3x3x3 local max); loss += softplus(x)*w
//        local-max test in logit space (monotone sigmoid; validated R3-R6, absmax 0.0)
//   pos: 64 coords/batch/level gather; w1=(1-sigmoid)^2; per-(b,tag) min of w1
// ws (floats): [0]=lossneg_a [1]=wneg_a [2]=lossneg_b [3]=wneg_b
//              [4]=losspos_a [5]=cntpos_a [6]=losspos_b [7]=cntpos_b [8]=block counter
// out: [0]=cls_loss_pos [1]=cls_loss_neg [2]=count_pos [3]=count_neg
//      [4]=wsum_pos [5]=wsum_neg [6..37]=pred_prob_min[2][B=2][T=8]
//
// R7 swizzle rationale: blocks dispatch round-robin across the 8 XCDs
// (xcd = bid % 8 heuristic). R3-R6 post-mortem: ~570 GB/s effective-fetch
// plateau + inverse occupancy/duration scaling = shared-resource wall at
// L2-miss/L3 traffic, because XCD-blind placement scatters the 27x-reuse
// stencil working set across all 8 private L2s. Remap so each XCD owns
// complete (vol, 8-z-slab) units, swept in y-order -> per-XCD hot window
// ~3 z-planes, halo crossing XCDs only 2 rows in 10.

#define NBLK_A 1024   // 4 vol x 16 z-slabs(8 z) x 16 y-chunks(8 y)
#define NBLK_B 128    // 4 vol x  4 z-blocks(16 z) x 8 y-chunks(8 y)
#define NBLK_TOTAL (NBLK_A + NBLK_B + 1)

__device__ __forceinline__ float fmax3(float a, float b, float c) {
    return fmaxf(a, fmaxf(b, c));
}

// One thread: fixed (x-quad, z), marches y0-1 .. y0+8 (10 rows, clamped),
// emitting 8 output rows. No LDS, no barriers; x-halo via wave shuffle on the
// z-folded column max (lane layout: xq contiguous within a z-group).
template <int D, int LOG2D, int XQ>
__device__ __forceinline__ void neg_march(
    const float* __restrict__ logits, const float* __restrict__ gt,
    int vol, int z, int y0, int xq, float& loss, float& wsum)
{
    const int x0 = xq << 2;
    const float* vb = logits + (vol << (3 * LOG2D));
    const int zm = z > 0 ? z - 1 : 0;
    const int zp = z < D - 1 ? z + 1 : z;
    const float* pzm = vb + (zm << (2 * LOG2D));
    const float* pz0 = vb + (z << (2 * LOG2D));
    const float* pzp = vb + (zp << (2 * LOG2D));
    const float* pg = gt + (vol << (3 * LOG2D)) + (z << (2 * LOG2D));

    float zw[3][4];   // ring: per-row column max over z-1,z,z+1
    float cc[2][4];   // ring: center-row (z) raw values
    float4 gg[2];     // ring: gt quads

#pragma unroll
    for (int s = 0; s < 10; ++s) {
        int yy = y0 - 1 + s;
        yy = yy < 0 ? 0 : (yy > D - 1 ? D - 1 : yy);
        const int ro = (yy << LOG2D) + x0;
        float4 r0 = *(const float4*)(pzm + ro);
        float4 r1 = *(const float4*)(pz0 + ro);
        float4 r2 = *(const float4*)(pzp + ro);
        if (s >= 1 && s <= 8) gg[s & 1] = *(const float4*)(pg + ro);
        zw[s % 3][0] = fmax3(r0.x, r1.x, r2.x);
        zw[s % 3][1] = fmax3(r0.y, r1.y, r2.y);
        zw[s % 3][2] = fmax3(r0.z, r1.z, r2.z);
        zw[s % 3][3] = fmax3(r0.w, r1.w, r2.w);
        cc[s & 1][0] = r1.x; cc[s & 1][1] = r1.y;
        cc[s & 1][2] = r1.z; cc[s & 1][3] = r1.w;
        if (s >= 2) {
            // output row y0+s-2: fold the 3 ring rows (y-window), then x-halo
            float cz0 = fmax3(zw[0][0], zw[1][0], zw[2][0]);
            float cz1 = fmax3(zw[0][1], zw[1][1], zw[2][1]);
            float cz2 = fmax3(zw[0][2], zw[1][2], zw[2][2]);
            float cz3 = fmax3(zw[0][3], zw[1][3], zw[2][3]);
            float lco = __shfl_up(cz3, 1);   if (xq == 0)      lco = cz0;
            float rco = __shfl_down(cz0, 1); if (xq == XQ - 1) rco = cz3;
            float m0 = fmax3(lco, cz0, cz1);
            float m1 = fmax3(cz0, cz1, cz2);
            float m2 = fmax3(cz1, cz2, cz3);
            float m3 = fmax3(cz2, cz3, rco);
            const float* c = cc[(s - 1) & 1];
            float4 gq = gg[(s - 1) & 1];
            float ms[4] = {m0, m1, m2, m3};
            float gs[4] = {gq.x, gq.y, gq.z, gq.w};
#pragma unroll
            for (int k = 0; k < 4; ++k) {
                if (gs[k] == -1.0f && ms[k] == c[k]) {
                    float e = __expf(c[k]);                  // e^x
                    float u = __builtin_amdgcn_rcpf(1.0f + e);
                    float sc = e * u;                        // sigmoid(x)
                    float wv = sc * sc;
                    wsum += wv;
                    loss += (-__logf(u)) * wv;               // softplus(x)
                }
            }
        }
    }
}

__global__ __launch_bounds__(256, 4) void fused_kernel(
    const float* __restrict__ la, const float* __restrict__ lb,
    const float* __restrict__ ga, const float* __restrict__ gb,
    const int* __restrict__ conn_a, const int* __restrict__ conn_b,
    const int* __restrict__ coord_a, const int* __restrict__ coord_b,
    float* __restrict__ ws, float* __restrict__ out)
{
    __shared__ float sred[8];
    __shared__ float w1s[128];
    __shared__ float tgf[128];
    const int bid = blockIdx.x;
    const int t = threadIdx.x;
    float loss = 0.0f, wsum = 0.0f;
    int accIdx = -1;

    if (bid < NBLK_A) {
        // level a: D=128. xq = t&31 (32 quads), zi = t>>5 (8 z per block).
        // XCD swizzle: xcd = bid&7 owns z-slabs {xcd, xcd+8} for all 4 vols,
        // y-chunks swept in-order within a slab (g&15 fastest).
        accIdx = 0;
        const int c = bid & 7;       // XCD id (dispatch heuristic bid % 8)
        const int g = bid >> 3;      // per-XCD sequence 0..127
        const int yc = g & 15;       // y sweeps fastest within a slab
        const int j = g >> 4;        // 0..7: (vol, slab-half) unit
        const int vol = j >> 1;
        const int zb = ((j & 1) << 3) | c;   // z-slab 0..15, tied to XCD
        neg_march<128, 7, 32>(la, ga, vol, zb * 8 + (t >> 5), yc * 8, t & 31,
                              loss, wsum);
    } else if (bid < NBLK_A + NBLK_B) {
        // level b: D=64 (8.4 MB total — fits L2s regardless; R4 mapping kept)
        accIdx = 2;
        const int b2 = bid - NBLK_A;
        const int vol = b2 >> 5;
        const int rem = b2 & 31;
        const int zb = rem >> 3, yc = rem & 7;
        neg_march<64, 6, 16>(lb, gb, vol, zb * 16 + (t >> 4), yc * 8, t & 15,
                             loss, wsum);
    } else {
        // pos block: both levels, 128 active threads
        for (int level = 0; level < 2; ++level) {
            const float* logits = level ? lb : la;
            const int* conn = level ? conn_b : conn_a;
            const int* coord = level ? coord_b : coord_a;
            const int D = level ? 64 : 128;
            float li = 0.0f, ci = 0.0f;
            if (t < 128) {
                const int* c4 = coord + t * 4;
                int a = c4[0], zz = c4[1], yy = c4[2], xx = c4[3];
                bool valid = a > -1;
                int aa = valid ? a : 0, z2 = valid ? zz : 0,
                    y2 = valid ? yy : 0, x2 = valid ? xx : 0;
                int b = t >> 6;
                int off = (((b * 2 + aa) * D + z2) * D + y2) * D + x2;
                float lp = logits[off];
                int tag = conn[off];
                float s = 1.0f / (1.0f + expf(lp));   // 1 - sigmoid(lp)
                float w1 = s * s;
                float vf = valid ? 1.0f : 0.0f;
                float sp = fmaxf(-lp, 0.0f) + log1pf(expf(-fabsf(lp)));  // softplus(-lp)
                li = sp * w1 * vf;
                ci = w1 * vf;
                w1s[t] = w1;
                tgf[t] = (float)(valid ? tag : -1);
            }
            for (int o = 32; o; o >>= 1) {
                li += __shfl_down(li, o);
                ci += __shfl_down(ci, o);
            }
            if ((t & 63) == 0) { sred[t >> 6] = li; sred[4 + (t >> 6)] = ci; }
            __syncthreads();
            if (t == 0) {
                atomicAdd(ws + 4 + 2 * level, sred[0] + sred[1] + sred[2] + sred[3]);
                atomicAdd(ws + 5 + 2 * level, sred[4] + sred[5] + sred[6] + sred[7]);
            }
            if (t < 16) {
                int bb = t >> 3, tg = t & 7;
                float mn = INFINITY;
                for (int i = 0; i < 64; ++i) {
                    int j = bb * 64 + i;
                    if (tgf[j] == (float)tg) mn = fminf(mn, w1s[j]);
                }
                out[6 + level * 16 + bb * 8 + tg] = isinf(mn) ? -1.0f : mn;
            }
            __syncthreads();
        }
    }

    if (accIdx >= 0) {
        for (int o = 32; o; o >>= 1) {
            loss += __shfl_down(loss, o);
            wsum += __shfl_down(wsum, o);
        }
        if ((t & 63) == 0) { sred[t >> 6] = loss; sred[4 + (t >> 6)] = wsum; }
        __syncthreads();
        if (t == 0) {
            float L = sred[0] + sred[1] + sred[2] + sred[3];
            float W = sred[4] + sred[5] + sred[6] + sred[7];
            if (L != 0.0f || W != 0.0f) {
                atomicAdd(ws + accIdx, L);
                atomicAdd(ws + accIdx + 1, W);
            }
        }
    }

    // last-block finalize
    if (t == 0) {
        __threadfence();
        unsigned int old = atomicAdd((unsigned int*)(ws + 8), 1u);
        if (old == NBLK_TOTAL - 1) {
            float s0 = atomicAdd(ws + 0, 0.0f);
            float s1 = atomicAdd(ws + 1, 0.0f);
            float s2 = atomicAdd(ws + 2, 0.0f);
            float s3 = atomicAdd(ws + 3, 0.0f);
            float s4 = atomicAdd(ws + 4, 0.0f);
            float s5 = atomicAdd(ws + 5, 0.0f);
            float s6 = atomicAdd(ws + 6, 0.0f);
            float s7 = atomicAdd(ws + 7, 0.0f);
            out[0] = s4 * 2.0f + s6;   // cls_loss_pos (POS_FACTOR {2,1})
            out[1] = s0 * 2.0f + s2;   // cls_loss_neg (NEG_FACTOR {2,1})
            out[2] = s5 + s7;          // count_pos
            out[3] = s1 + s3;          // count_neg
            out[4] = s5 * 2.0f + s7;   // wsum_pos (anchor factor == 1)
            out[5] = s1 * 2.0f + s3;   // wsum_neg
        }
    }
}

extern "C" void kernel_launch(void* const* d_in, const int* in_sizes, int n_in,
                              void* d_out, int out_size, void* d_ws, size_t ws_size,
                              hipStream_t stream) {
    const float* logits_a = (const float*)d_in[0];
    const float* logits_b = (const float*)d_in[1];
    const float* prob_a   = (const float*)d_in[2];
    const float* prob_b   = (const float*)d_in[3];
    const int*   conn_a   = (const int*)d_in[4];
    const int*   conn_b   = (const int*)d_in[5];
    const int*   coord_a  = (const int*)d_in[6];
    const int*   coord_b  = (const int*)d_in[7];
    float* out = (float*)d_out;
    float* ws  = (float*)d_ws;

    hipMemsetAsync(ws, 0, 12 * sizeof(float), stream);
    fused_kernel<<<NBLK_TOTAL, 256, 0, stream>>>(
        logits_a, logits_b, prob_a, prob_b,
        conn_a, conn_b, coord_a, coord_b, ws, out);
}